// Round 8
// baseline (2013.004 us; speedup 1.0000x reference)
//
#include <hip/hip_runtime.h>
#include <float.h>

#define BB 32
#define MMv 512
#define LLv 512
#define DDv 128
#define HHv 8
#define DFFv 256
#define KNB 16
#define NLAY 2
#define NNODE (BB*MMv)       // 16384
#define TOTE  (NNODE*KNB)    // 262144 edges

typedef unsigned short ushort_t;
typedef unsigned int u32;

__device__ __forceinline__ float bf2f(ushort_t u){
  union { u32 i; float f; } x; x.i = ((u32)u) << 16; return x.f;
}
__device__ __forceinline__ float ldx(const void* p, size_t i, int f32){
  return f32 ? ((const float*)p)[i] : bf2f(((const ushort_t*)p)[i]);
}

// ---- diagnostics (fp32 output now) ----
__global__ __launch_bounds__(256) void diag_fill_k(float* out, int n, float val){
  for(int i = blockIdx.x*256 + threadIdx.x; i < n; i += gridDim.x*256) out[i] = val;
}

// ---- per-input dtype detection (one block per input) ----
struct P18 { const ushort_t* p[18]; int n[18]; };
__global__ __launch_bounds__(256) void ddet_k(P18 a, int* DF){
  int i = blockIdx.x;
  const ushort_t* q = a.p[i];
  int P = min(a.n[i], 4096);
  int t = threadIdx.x;
  int r1 = 0, evenNZ = 0, oddNZ = 0;
  for(int j=t; j<P; j+=256){
    ushort_t v = q[j];
    if(((v >> 7) & 0xFF) >= 0xC0) r1 = 1;   // impossible exponent for real bf16 data
    if(v){ if(j & 1) oddNZ = 1; else evenNZ = 1; }
  }
  __shared__ int sh[3];
  if(t==0){ sh[0]=0; sh[1]=0; sh[2]=0; }
  __syncthreads();
  if(r1) atomicOr(&sh[0],1);
  if(evenNZ) atomicOr(&sh[1],1);
  if(oddNZ) atomicOr(&sh[2],1);
  __syncthreads();
  if(t==0) DF[i] = sh[0] | ((sh[1]==0) & (sh[2]!=0));
}

// ---- fp64 per-(b,m) column sum + reciprocal std of x_enc columns ----
__global__ __launch_bounds__(256) void stats64_k(const void* xe, const int* DF,
                                                 double* S64, double* R64){
  int f32 = DF[1];
  int tid = blockIdx.x*256 + threadIdx.x;   // b*512+n
  int b = tid >> 9, n = tid & 511;
  size_t base = (size_t)b*LLv*MMv;
  double s = 0.0, ss = 0.0;
  for(int l=0;l<LLv;l++){
    double x = (double)ldx(xe, base + (size_t)l*MMv + n, f32);
    s += x; ss += x*x;
  }
  S64[tid] = s;
  double cov = (ss - s*s*(1.0/LLv)) * (1.0/(LLv-1));
  double sd = (cov > 0.0) ? sqrt(cov) : 0.0;
  R64[tid] = (sd > 0.0) ? (1.0/sd) : 1.0;
}

// ---- fp64 corr row + top-(K+1)-smallest selection. One block per (m, b). ----
__global__ __launch_bounds__(256) void corrsel64_k(const void* xe, const double* S64,
                                                   const double* R64, int* nbr, const int* DF){
  __shared__ float  xm[512];
  __shared__ double cr[512];
  __shared__ double redv[256];
  __shared__ int    redi[256];
  int f32 = DF[1];
  int m = blockIdx.x, b = blockIdx.y;
  int t = threadIdx.x;
  size_t base = (size_t)b*LLv*MMv;
  xm[t]     = ldx(xe, base + (size_t)t*MMv + m, f32);
  xm[t+256] = ldx(xe, base + (size_t)(t+256)*MMv + m, f32);
  __syncthreads();
  int n0 = t, n1 = t + 256;
  double a0 = 0.0, a1 = 0.0;
  for(int l=0;l<512;l++){
    double xl = (double)xm[l];
    size_t rowb = base + (size_t)l*MMv;
    a0 += xl * (double)ldx(xe, rowb + n0, f32);
    a1 += xl * (double)ldx(xe, rowb + n1, f32);
  }
  const double* Sb = S64 + b*MMv;
  const double* Rb = R64 + b*MMv;
  double sm = Sb[m], rm = Rb[m];
  cr[n0] = ((a0 - sm*Sb[n0]*(1.0/LLv))*(1.0/(LLv-1))) * rm * Rb[n0];
  cr[n1] = ((a1 - sm*Sb[n1]*(1.0/LLv))*(1.0/(LLv-1))) * rm * Rb[n1];
  __syncthreads();
  double v0 = cr[n0], v1 = cr[n1];
  for(int it=0; it<=KNB; it++){
    double bv; int bi;
    if(v0 < v1 || (v0 == v1 && n0 < n1)){ bv = v0; bi = n0; } else { bv = v1; bi = n1; }
    redv[t] = bv; redi[t] = bi;
    __syncthreads();
    for(int st=128; st>=1; st>>=1){
      if(t < st){
        double ov = redv[t+st]; int oi = redi[t+st];
        if(ov < redv[t] || (ov == redv[t] && oi < redi[t])){ redv[t]=ov; redi[t]=oi; }
      }
      __syncthreads();
    }
    int gbi = redi[0];
    __syncthreads();
    if(it > 0 && t == 0) nbr[(size_t)(b*MMv + m)*KNB + it-1] = min(max(gbi,0), MMv-1);
    if(gbi == n0) v0 = DBL_MAX;
    if(gbi == n1) v1 = DBL_MAX;
  }
}

// ---- graph build (all data-dependent indices clamped) ----
__global__ __launch_bounds__(256) void zero_k(int* p){
  p[blockIdx.x*256 + threadIdx.x] = 0;
}

__global__ __launch_bounds__(256) void hist_k(const int* nbr, int* cnt){
  int tid = blockIdx.x*256 + threadIdx.x;
  int b = tid >> 13;
  int col = min(max(nbr[tid], 0), MMv-1);
  atomicAdd(&cnt[b*MMv + col], 1);
}

__global__ __launch_bounds__(256) void scan_k(const int* cnt, int* off,
                                              int* cursor, float* dinv){
  __shared__ int part[256];
  int t = threadIdx.x;
  int base = t*64, s = 0;
  for(int i=0;i<64;i++) s += cnt[base+i];
  part[t] = s; __syncthreads();
  for(int st=1; st<256; st<<=1){
    int v = (t >= st) ? part[t-st] : 0;
    __syncthreads();
    part[t] += v; __syncthreads();
  }
  int run = (t > 0) ? part[t-1] : 0;
  for(int i=0;i<64;i++){
    int idx = base+i;
    off[idx] = run; cursor[idx] = run;
    run += cnt[idx];
    dinv[idx] = 1.0f/sqrtf((float)(cnt[idx]+1));   // +1 self loop
  }
  if(t == 255) off[NNODE] = run;
}

__global__ __launch_bounds__(256) void fill_k(const int* nbr, int* cursor, int* esrc){
  int tid = blockIdx.x*256 + threadIdx.x;   // edge: b*8192 + e, e = m*16+k
  int b = tid >> 13;
  int rem = tid & 8191;
  int col = min(max(nbr[tid], 0), MMv-1);
  int dst = b*MMv + col;
  int srcl = rem & 511;                      // src = e mod 512 (faithful tile() quirk)
  int pos = atomicAdd(&cursor[dst], 1);
  pos = min(max(pos, 0), TOTE-1);
  esrc[pos] = b*MMv + srcl;
}

// ---- fp32 GEMM: C[N,Dout] = A[N,Kd] * W[Kd,Dout] (+bias)(+relu); W/bias dtype via DF ----
__global__ __launch_bounds__(256) void gemm_k(const float* A, const void* W,
                                              size_t woff, int wdi, const void* bias, int boff, int bdi,
                                              float* C, int Kd, int Dout, int relu,
                                              const int* DF){
  __shared__ float As[16*68];
  __shared__ float Ws[16*68];
  int wf32 = DF[wdi];
  int bf32 = DF[bdi];
  int m0 = blockIdx.y*64, n0 = blockIdx.x*64;
  int tx = threadIdx.x, ty = threadIdx.y;
  int t = ty*16 + tx;
  float acc[4][4] = {};
  int ar = t >> 2, ac4 = (t & 3)*4;
  int wk = t >> 4, wc4 = (t & 15)*4;
  for(int k0=0; k0<Kd; k0+=16){
    const float* ap = &A[(size_t)(m0+ar)*Kd + k0 + ac4];
    size_t wbase = woff + (size_t)(k0+wk)*Dout + n0 + wc4;
    As[(ac4+0)*68+ar] = ap[0]; As[(ac4+1)*68+ar] = ap[1];
    As[(ac4+2)*68+ar] = ap[2]; As[(ac4+3)*68+ar] = ap[3];
    Ws[wk*68+wc4+0] = ldx(W, wbase+0, wf32); Ws[wk*68+wc4+1] = ldx(W, wbase+1, wf32);
    Ws[wk*68+wc4+2] = ldx(W, wbase+2, wf32); Ws[wk*68+wc4+3] = ldx(W, wbase+3, wf32);
    __syncthreads();
    #pragma unroll
    for(int k=0;k<16;k++){
      float4 a = *(const float4*)&As[k*68 + ty*4];
      float4 w = *(const float4*)&Ws[k*68 + tx*4];
      float avr[4] = {a.x,a.y,a.z,a.w};
      float wvr[4] = {w.x,w.y,w.z,w.w};
      #pragma unroll
      for(int i=0;i<4;i++)
        #pragma unroll
        for(int j=0;j<4;j++)
          acc[i][j] = fmaf(avr[i], wvr[j], acc[i][j]);
    }
    __syncthreads();
  }
  #pragma unroll
  for(int i=0;i<4;i++){
    #pragma unroll
    for(int j=0;j<4;j++){
      int n = n0 + tx*4 + j;
      float v = acc[i][j];
      if(bias) v += ldx(bias, boff + n, bf32);
      if(relu) v = fmaxf(v, 0.f);
      C[(size_t)(m0+ty*4+i)*Dout + n] = v;
    }
  }
}

// ---- GCN aggregation (fp32, clamped gather; bias dtype via DF[bdi]) ----
__global__ __launch_bounds__(256) void agg_k(const float* xw, const int* off,
                                             const int* esrc, const float* dinv,
                                             const void* bias, int bdi, float* out,
                                             const int* DF){
  int f32 = DF[bdi];
  int node = blockIdx.x*4 + (threadIdx.x >> 6);
  int lane = threadIdx.x & 63;
  float dn = dinv[node];
  float a0 = dn*dn*xw[(size_t)node*DDv + 2*lane];
  float a1 = dn*dn*xw[(size_t)node*DDv + 2*lane+1];
  int e0 = min(max(off[node], 0), TOTE);
  int e1 = min(max(off[node+1], e0), TOTE);
  for(int e=e0; e<e1; e++){
    int s = min(max(esrc[e], 0), NNODE-1);
    float w = dinv[s]*dn;
    a0 = fmaf(w, xw[(size_t)s*DDv + 2*lane],   a0);
    a1 = fmaf(w, xw[(size_t)s*DDv + 2*lane+1], a1);
  }
  a0 += ldx(bias, 2*lane, f32); a1 += ldx(bias, 2*lane+1, f32);
  out[(size_t)node*DDv + 2*lane]   = fmaxf(a0, 0.f);
  out[(size_t)node*DDv + 2*lane+1] = fmaxf(a1, 0.f);
}

// ---- cross-attention per (b, head): fp32, per-thread online softmax ----
__global__ __launch_bounds__(256) void attn_k(const float* qg, const float* kg,
                                              const float* vg, float* og){
  __shared__ float Ks[512*16];
  __shared__ float Vs[512*16];
  int bh = blockIdx.x; int b = bh >> 3, hh = bh & 7;
  size_t base = (size_t)b*MMv*DDv + (size_t)hh*16;
  int t = threadIdx.x;
  for(int idx=t; idx<512*16; idx+=256){
    int kk = idx >> 4, i = idx & 15;
    Ks[idx] = kg[base + (size_t)kk*DDv + i];
    Vs[idx] = vg[base + (size_t)kk*DDv + i];
  }
  __syncthreads();
  for(int r=t; r<MMv; r+=256){
    float qr[16];
    #pragma unroll
    for(int i=0;i<16;i++) qr[i] = qg[base + (size_t)r*DDv + i];
    float m = -FLT_MAX, l = 0.f, acc[16] = {};
    for(int kk=0; kk<512; kk++){
      const float* kp = &Ks[kk*16];
      float s = 0.f;
      #pragma unroll
      for(int i=0;i<16;i++) s = fmaf(qr[i], kp[i], s);
      s *= 0.25f;
      float mn = fmaxf(m, s);
      float cold = __expf(m - mn);
      float p = __expf(s - mn);
      l = l*cold + p;
      const float* vp = &Vs[kk*16];
      #pragma unroll
      for(int i=0;i<16;i++) acc[i] = acc[i]*cold + p*vp[i];
      m = mn;
    }
    float inv = 1.0f/l;
    #pragma unroll
    for(int i=0;i<16;i++) og[base + (size_t)r*DDv + i] = acc[i]*inv;
  }
}

// ---- residual + LayerNorm: one thread per row, fp32 in/out; g/b dtype via DF ----
__global__ __launch_bounds__(256) void ln_k(const float* h, const float* delta,
                                            const void* g, int gdi, const void* bb, int bdi, int po,
                                            float* dst, const int* DF){
  int gf32 = DF[gdi], bf32 = DF[bdi];
  int row = blockIdx.x*256 + threadIdx.x;
  const float* hr = h + (size_t)row*DDv;
  const float* dr = delta + (size_t)row*DDv;
  float s = 0.f, ss = 0.f;
  for(int i=0;i<DDv;i++){
    float xv = hr[i] + dr[i];
    s += xv; ss = fmaf(xv, xv, ss);
  }
  float mu = s*(1.0f/DDv);
  float var = fmaxf(ss*(1.0f/DDv) - mu*mu, 0.f);
  float rs = 1.0f/sqrtf(var + 1e-5f);
  for(int i=0;i<DDv;i++){
    float xv = hr[i] + dr[i];
    dst[(size_t)row*DDv + i] = (xv - mu)*rs*ldx(g, po+i, gf32) + ldx(bb, po+i, bf32);
  }
}

// ---- enc -> fp32 h ----
__global__ __launch_bounds__(256) void cvt_k(const void* in, float* out, const int* DF){
  int f32 = DF[0];
  int tid = blockIdx.x*256 + threadIdx.x;
  out[tid] = ldx(in, tid, f32);
}

extern "C" void kernel_launch(void* const* d_in, const int* in_sizes, int n_in,
                              void* d_out, int out_size, void* d_ws, size_t ws_size,
                              hipStream_t stream) {
  if(n_in != 18){
    diag_fill_k<<<256, 256, 0, stream>>>((float*)d_out, out_size, 1000.0f);
    return;
  }
  const int expect[18] = {
    BB*MMv*DDv, BB*LLv*MMv, DDv*DDv, DDv, DDv*DDv, DDv,
    NLAY*DDv*DDv, NLAY*DDv*DDv, NLAY*DDv*DDv, NLAY*DDv*DDv,
    NLAY*DDv*DFFv, NLAY*DFFv, NLAY*DFFv*DDv, NLAY*DDv,
    NLAY*DDv, NLAY*DDv, NLAY*DDv, NLAY*DDv
  };
  for(int i=0;i<18;i++){
    if(in_sizes[i] != expect[i]){
      diag_fill_k<<<256, 256, 0, stream>>>((float*)d_out, out_size, 2000.0f + 10.0f*i);
      return;
    }
  }

  const void* enc  = d_in[0];
  const void* xe   = d_in[1];
  const void* c1W  = d_in[2];
  const void* c1b  = d_in[3];
  const void* c2W  = d_in[4];
  const void* c2b  = d_in[5];
  const void* Wq   = d_in[6];
  const void* Wk   = d_in[7];
  const void* Wv   = d_in[8];
  const void* Wo   = d_in[9];
  const void* W1   = d_in[10];
  const void* b1   = d_in[11];
  const void* W2   = d_in[12];
  const void* b2   = d_in[13];
  const void* ln1g = d_in[14];
  const void* ln1b = d_in[15];
  const void* ln2g = d_in[16];
  const void* ln2b = d_in[17];

  char* ws = (char*)d_ws;
  size_t o = 0;
  auto alloc = [&](size_t bytes){ size_t r = o; o = (o + bytes + 255) & ~(size_t)255; return r; };
  double* S64  = (double*)(ws + alloc((size_t)NNODE*8));
  double* R64  = (double*)(ws + alloc((size_t)NNODE*8));
  float* dinv  = (float*)(ws + alloc((size_t)NNODE*4));
  int*   cnt   = (int*)  (ws + alloc((size_t)NNODE*4));
  int*   cursor= (int*)  (ws + alloc((size_t)NNODE*4));
  int*   off   = (int*)  (ws + alloc((size_t)(NNODE+1)*4));
  int*   nbr   = (int*)  (ws + alloc((size_t)TOTE*4));
  int*   esrc  = (int*)  (ws + alloc((size_t)TOTE*4));
  int*   DF    = (int*)  (ws + alloc(256));
  const size_t ACTF = (size_t)NNODE*DDv*4;   // fp32 activation: 8.39 MB
  float* hF = (float*)(ws + alloc(ACTF));
  float* xg = (float*)(ws + alloc(ACTF));
  float* t0 = (float*)(ws + alloc(ACTF));
  float* t1 = (float*)(ws + alloc(ACTF));
  float* t2 = (float*)(ws + alloc(ACTF));    // t1+t2 contiguous -> ffn hidden fp32 [NNODE,DFF]
  float* t3 = (float*)(ws + alloc(ACTF));
  float* fb = t1;                             // 16.78 MB span; k/v dead when ffn runs
  if(ws_size < o){
    diag_fill_k<<<256, 256, 0, stream>>>((float*)d_out, out_size, 3000.0f);
    return;
  }

  // ---- per-input dtype detection ----
  P18 pack;
  for(int i=0;i<18;i++){ pack.p[i] = (const ushort_t*)d_in[i]; pack.n[i] = in_sizes[i]; }
  ddet_k<<<18, 256, 0, stream>>>(pack, DF);

  // --- graph construction (fp64 corr + selection) ---
  stats64_k<<<NNODE/256, 256, 0, stream>>>(xe, DF, S64, R64);
  corrsel64_k<<<dim3(MMv, BB), 256, 0, stream>>>(xe, S64, R64, nbr, DF);
  zero_k<<<NNODE/256, 256, 0, stream>>>(cnt);
  hist_k<<<TOTE/256, 256, 0, stream>>>(nbr, cnt);
  scan_k<<<1, 256, 0, stream>>>(cnt, off, cursor, dinv);
  fill_k<<<TOTE/256, 256, 0, stream>>>(nbr, cursor, esrc);

  // --- GCN (2 layers, fp32) ---
  cvt_k<<<NNODE*DDv/256, 256, 0, stream>>>(enc, hF, DF);
  gemm_k<<<dim3(2,256), dim3(16,16), 0, stream>>>(hF, c1W, 0, 2, nullptr, 0, 3, t0, DDv, DDv, 0, DF);
  agg_k<<<NNODE/4, 256, 0, stream>>>(t0, off, esrc, dinv, c1b, 3, t1, DF);
  gemm_k<<<dim3(2,256), dim3(16,16), 0, stream>>>(t1, c2W, 0, 4, nullptr, 0, 5, t0, DDv, DDv, 0, DF);
  agg_k<<<NNODE/4, 256, 0, stream>>>(t0, off, esrc, dinv, c2b, 5, xg, DF);

  // --- transformer (2 layers, fp32 end-to-end; query stream = hF, kv = xg) ---
  for(int l=0; l<NLAY; l++){
    gemm_k<<<dim3(2,256), dim3(16,16), 0, stream>>>(hF, Wq, (size_t)l*DDv*DDv, 6, nullptr, 0, 6, t0, DDv, DDv, 0, DF);
    gemm_k<<<dim3(2,256), dim3(16,16), 0, stream>>>(xg, Wk, (size_t)l*DDv*DDv, 7, nullptr, 0, 7, t1, DDv, DDv, 0, DF);
    gemm_k<<<dim3(2,256), dim3(16,16), 0, stream>>>(xg, Wv, (size_t)l*DDv*DDv, 8, nullptr, 0, 8, t2, DDv, DDv, 0, DF);
    attn_k<<<BB*HHv, 256, 0, stream>>>(t0, t1, t2, t3);
    gemm_k<<<dim3(2,256), dim3(16,16), 0, stream>>>(t3, Wo, (size_t)l*DDv*DDv, 9, nullptr, 0, 9, t0, DDv, DDv, 0, DF);
    ln_k<<<NNODE/256, 256, 0, stream>>>(hF, t0, ln1g, 14, ln1b, 15, l*DDv, hF, DF);
    gemm_k<<<dim3(4,256), dim3(16,16), 0, stream>>>(hF, W1, (size_t)l*DDv*DFFv, 10, b1, l*DFFv, 11, fb, DDv, DFFv, 1, DF);
    gemm_k<<<dim3(2,256), dim3(16,16), 0, stream>>>(fb, W2, (size_t)l*DFFv*DDv, 12, b2, l*DDv, 13, t0, DFFv, DDv, 0, DF);
    float* dst = (l == NLAY-1) ? (float*)d_out : hF;
    ln_k<<<NNODE/256, 256, 0, stream>>>(hF, t0, ln2g, 16, ln2b, 17, l*DDv, dst, DF);
  }
}

// Round 9
// 1421.925 us; speedup vs baseline: 1.4157x; 1.4157x over previous
//
#include <hip/hip_runtime.h>
#include <float.h>

#define BB 32
#define MMv 512
#define LLv 512
#define DDv 128
#define HHv 8
#define DFFv 256
#define KNB 16
#define NLAY 2
#define NNODE (BB*MMv)       // 16384
#define TOTE  (NNODE*KNB)    // 262144 edges

typedef unsigned short ushort_t;
typedef unsigned int u32;
typedef __attribute__((ext_vector_type(8))) short bf16x8;
typedef __attribute__((ext_vector_type(4))) float f32x4;

__device__ __forceinline__ float bf2f(ushort_t u){
  union { u32 i; float f; } x; x.i = ((u32)u) << 16; return x.f;
}
__device__ __forceinline__ ushort_t f2bf(float f){
  union { u32 i; float f; } x; x.f = f;
  u32 r = x.i + 0x7FFFu + ((x.i >> 16) & 1u);   // RNE
  return (ushort_t)(r >> 16);
}
__device__ __forceinline__ float ldx(const void* p, size_t i, int f32){
  return f32 ? ((const float*)p)[i] : bf2f(((const ushort_t*)p)[i]);
}

// ---- diagnostics (fp32 output) ----
__global__ __launch_bounds__(256) void diag_fill_k(float* out, int n, float val){
  for(int i = blockIdx.x*256 + threadIdx.x; i < n; i += gridDim.x*256) out[i] = val;
}

// ---- per-input dtype detection (one block per input) ----
struct P18 { const ushort_t* p[18]; int n[18]; };
__global__ __launch_bounds__(256) void ddet_k(P18 a, int* DF){
  int i = blockIdx.x;
  const ushort_t* q = a.p[i];
  int P = min(a.n[i], 4096);
  int t = threadIdx.x;
  int r1 = 0, evenNZ = 0, oddNZ = 0;
  for(int j=t; j<P; j+=256){
    ushort_t v = q[j];
    if(((v >> 7) & 0xFF) >= 0xC0) r1 = 1;   // impossible exponent for real bf16 data
    if(v){ if(j & 1) oddNZ = 1; else evenNZ = 1; }
  }
  __shared__ int sh[3];
  if(t==0){ sh[0]=0; sh[1]=0; sh[2]=0; }
  __syncthreads();
  if(r1) atomicOr(&sh[0],1);
  if(evenNZ) atomicOr(&sh[1],1);
  if(oddNZ) atomicOr(&sh[2],1);
  __syncthreads();
  if(t==0) DF[i] = sh[0] | ((sh[1]==0) & (sh[2]!=0));
}

// ---- split-transpose: x_enc[B,L,M] -> Xhi/Xlo[B,M,L] (x ~= hi+lo, ~2^-17 rel exact) ----
__global__ __launch_bounds__(256) void split_k(const void* xe, ushort_t* Xhi,
                                               ushort_t* Xlo, const int* DF){
  __shared__ ushort_t th[32][33];
  __shared__ ushort_t tl[32][33];
  int f32 = DF[1];
  int b = blockIdx.z;
  int m0 = blockIdx.x*32, l0 = blockIdx.y*32;
  int tx = threadIdx.x, ty = threadIdx.y;   // 32 x 8
  #pragma unroll
  for(int i=0;i<4;i++){
    int l = l0+ty+8*i, m = m0+tx;
    float x = ldx(xe, (size_t)b*LLv*MMv + (size_t)l*MMv + m, f32);
    ushort_t hi = f2bf(x);
    ushort_t lo = f2bf(x - bf2f(hi));
    th[ty+8*i][tx] = hi; tl[ty+8*i][tx] = lo;
  }
  __syncthreads();
  #pragma unroll
  for(int i=0;i<4;i++){
    size_t d = (size_t)b*MMv*LLv + (size_t)(m0+ty+8*i)*LLv + l0+tx;
    Xhi[d] = th[tx][ty+8*i];
    Xlo[d] = tl[tx][ty+8*i];
  }
}

// ---- fp64 per-(b,n) column sum + reciprocal std (cheap; keep r8-validated) ----
__global__ __launch_bounds__(256) void stats64_k(const void* xe, const int* DF,
                                                 double* S64, double* R64){
  int f32 = DF[1];
  int tid = blockIdx.x*256 + threadIdx.x;   // b*512+n
  int b = tid >> 9, n = tid & 511;
  size_t base = (size_t)b*LLv*MMv;
  double s = 0.0, ss = 0.0;
  for(int l=0;l<LLv;l++){
    double x = (double)ldx(xe, base + (size_t)l*MMv + n, f32);
    s += x; ss += x*x;
  }
  S64[tid] = s;
  double cov = (ss - s*s*(1.0/LLv)) * (1.0/(LLv-1));
  double sd = (cov > 0.0) ? sqrt(cov) : 0.0;
  R64[tid] = (sd > 0.0) ? (1.0/sd) : 1.0;
}

// ---- MFMA corr strip (split-bf16: hi*hi + hi*lo + lo*hi) + top-(K+1)-smallest selection ----
// block = (strip of 16 rows m) x (batch b); selection semantics identical to r8's validated kernel.
__global__ __launch_bounds__(256) void corrsel_k(const ushort_t* Xhi, const ushort_t* Xlo,
                                                 const double* S64, const double* R64,
                                                 int* nbr, const int* DF){
  __shared__ float Cs[16*516];
  __shared__ float redv[256];
  __shared__ int   redi[256];
  int f32 = DF[1];
  int strip = blockIdx.x, b = blockIdx.y;
  int m0 = strip*16;
  int t = threadIdx.x;
  int wave = t >> 6, lane = t & 63;
  int quad = lane >> 4, l16 = lane & 15;
  const ushort_t* Hb = Xhi + (size_t)b*MMv*LLv;
  const ushort_t* Lb = Xlo + (size_t)b*MMv*LLv;
  const double* Sb = S64 + b*MMv;
  const double* Rb = R64 + b*MMv;
  size_t arow = (size_t)(m0 + l16)*LLv;     // A fragment: row m = m0 + (lane&15), k-chunk = quad*8
  for(int ct=0; ct<8; ct++){
    int n0 = ct*64;
    size_t brow = (size_t)(n0 + wave*16 + l16)*LLv;   // B fragment: col n
    f32x4 acc = {0.f,0.f,0.f,0.f};
    for(int k0=0;k0<LLv;k0+=32){
      int ko = k0 + quad*8;
      bf16x8 ah = *(const bf16x8*)&Hb[arow + ko];
      bf16x8 bh = *(const bf16x8*)&Hb[brow + ko];
      acc = __builtin_amdgcn_mfma_f32_16x16x32_bf16(ah, bh, acc, 0, 0, 0);
      if(f32){   // fp32 inputs: add cross terms for ~2^-17 rel accuracy
        bf16x8 al = *(const bf16x8*)&Lb[arow + ko];
        bf16x8 bl = *(const bf16x8*)&Lb[brow + ko];
        acc = __builtin_amdgcn_mfma_f32_16x16x32_bf16(ah, bl, acc, 0, 0, 0);
        acc = __builtin_amdgcn_mfma_f32_16x16x32_bf16(al, bh, acc, 0, 0, 0);
      }
    }
    int n = n0 + wave*16 + l16;
    float sn = (float)(Sb[n]*(1.0/LLv));
    float rn = (float)Rb[n];
    #pragma unroll
    for(int r=0;r<4;r++){
      int ml = quad*4 + r;                  // C/D layout: row = quad*4 + reg (m), col = lane&15 (n)
      float cov = (acc[r] - (float)Sb[m0+ml]*sn) * (1.0f/(LLv-1));
      Cs[ml*516 + n] = cov * (float)Rb[m0+ml] * rn;
    }
  }
  __syncthreads();
  // selection: wave w handles rows w*4..w*4+3; iterative stable argmin via per-wave LDS tree
  for(int rr=0; rr<4; rr++){
    int r = wave*4 + rr;
    float vals[8];
    #pragma unroll
    for(int j=0;j<8;j++) vals[j] = Cs[r*516 + lane + 64*j];
    for(int it=0; it<=KNB; it++){
      float bvv = FLT_MAX; int bi = 0x7fffffff;
      #pragma unroll
      for(int j=0;j<8;j++){
        int n = lane + 64*j;
        if(vals[j] < bvv){ bvv = vals[j]; bi = n; }
      }
      redv[t] = bvv; redi[t] = bi;
      __syncthreads();
      #pragma unroll
      for(int stride=32; stride>=1; stride>>=1){
        if(lane < stride){
          float v2 = redv[t+stride]; int i2 = redi[t+stride];
          if(v2 < redv[t] || (v2 == redv[t] && i2 < redi[t])){ redv[t]=v2; redi[t]=i2; }
        }
        __syncthreads();
      }
      int gbi = redi[wave*64];
      __syncthreads();
      int bic = min(max(gbi, 0), MMv-1);    // clamp: bad data -> wrong answer, never a fault
      if(it > 0 && lane == 0) nbr[(size_t)(b*MMv + m0 + r)*KNB + it-1] = bic;
      if((gbi & 63) == lane && gbi < MMv) vals[gbi >> 6] = FLT_MAX;
    }
  }
}

// ---- graph build (all data-dependent indices clamped) ----
__global__ __launch_bounds__(256) void zero_k(int* p){
  p[blockIdx.x*256 + threadIdx.x] = 0;
}

__global__ __launch_bounds__(256) void hist_k(const int* nbr, int* cnt){
  int tid = blockIdx.x*256 + threadIdx.x;
  int b = tid >> 13;
  int col = min(max(nbr[tid], 0), MMv-1);
  atomicAdd(&cnt[b*MMv + col], 1);
}

__global__ __launch_bounds__(256) void scan_k(const int* cnt, int* off,
                                              int* cursor, float* dinv){
  __shared__ int part[256];
  int t = threadIdx.x;
  int base = t*64, s = 0;
  for(int i=0;i<64;i++) s += cnt[base+i];
  part[t] = s; __syncthreads();
  for(int st=1; st<256; st<<=1){
    int v = (t >= st) ? part[t-st] : 0;
    __syncthreads();
    part[t] += v; __syncthreads();
  }
  int run = (t > 0) ? part[t-1] : 0;
  for(int i=0;i<64;i++){
    int idx = base+i;
    off[idx] = run; cursor[idx] = run;
    run += cnt[idx];
    dinv[idx] = 1.0f/sqrtf((float)(cnt[idx]+1));   // +1 self loop
  }
  if(t == 255) off[NNODE] = run;
}

__global__ __launch_bounds__(256) void fill_k(const int* nbr, int* cursor, int* esrc){
  int tid = blockIdx.x*256 + threadIdx.x;   // edge: b*8192 + e, e = m*16+k
  int b = tid >> 13;
  int rem = tid & 8191;
  int col = min(max(nbr[tid], 0), MMv-1);
  int dst = b*MMv + col;
  int srcl = rem & 511;                      // src = e mod 512 (faithful tile() quirk)
  int pos = atomicAdd(&cursor[dst], 1);
  pos = min(max(pos, 0), TOTE-1);
  esrc[pos] = b*MMv + srcl;
}

// ---- fp32 GEMM: C[N,Dout] = A[N,Kd] * W[Kd,Dout] (+bias)(+relu); W/bias dtype via DF ----
__global__ __launch_bounds__(256) void gemm_k(const float* A, const void* W,
                                              size_t woff, int wdi, const void* bias, int boff, int bdi,
                                              float* C, int Kd, int Dout, int relu,
                                              const int* DF){
  __shared__ float As[16*68];
  __shared__ float Ws[16*68];
  int wf32 = DF[wdi];
  int bf32 = DF[bdi];
  int m0 = blockIdx.y*64, n0 = blockIdx.x*64;
  int tx = threadIdx.x, ty = threadIdx.y;
  int t = ty*16 + tx;
  float acc[4][4] = {};
  int ar = t >> 2, ac4 = (t & 3)*4;
  int wk = t >> 4, wc4 = (t & 15)*4;
  for(int k0=0; k0<Kd; k0+=16){
    const float* ap = &A[(size_t)(m0+ar)*Kd + k0 + ac4];
    size_t wbase = woff + (size_t)(k0+wk)*Dout + n0 + wc4;
    As[(ac4+0)*68+ar] = ap[0]; As[(ac4+1)*68+ar] = ap[1];
    As[(ac4+2)*68+ar] = ap[2]; As[(ac4+3)*68+ar] = ap[3];
    Ws[wk*68+wc4+0] = ldx(W, wbase+0, wf32); Ws[wk*68+wc4+1] = ldx(W, wbase+1, wf32);
    Ws[wk*68+wc4+2] = ldx(W, wbase+2, wf32); Ws[wk*68+wc4+3] = ldx(W, wbase+3, wf32);
    __syncthreads();
    #pragma unroll
    for(int k=0;k<16;k++){
      float4 a = *(const float4*)&As[k*68 + ty*4];
      float4 w = *(const float4*)&Ws[k*68 + tx*4];
      float avr[4] = {a.x,a.y,a.z,a.w};
      float wvr[4] = {w.x,w.y,w.z,w.w};
      #pragma unroll
      for(int i=0;i<4;i++)
        #pragma unroll
        for(int j=0;j<4;j++)
          acc[i][j] = fmaf(avr[i], wvr[j], acc[i][j]);
    }
    __syncthreads();
  }
  #pragma unroll
  for(int i=0;i<4;i++){
    #pragma unroll
    for(int j=0;j<4;j++){
      int n = n0 + tx*4 + j;
      float v = acc[i][j];
      if(bias) v += ldx(bias, boff + n, bf32);
      if(relu) v = fmaxf(v, 0.f);
      C[(size_t)(m0+ty*4+i)*Dout + n] = v;
    }
  }
}

// ---- GCN aggregation (fp32, clamped gather; bias dtype via DF[bdi]) ----
__global__ __launch_bounds__(256) void agg_k(const float* xw, const int* off,
                                             const int* esrc, const float* dinv,
                                             const void* bias, int bdi, float* out,
                                             const int* DF){
  int f32 = DF[bdi];
  int node = blockIdx.x*4 + (threadIdx.x >> 6);
  int lane = threadIdx.x & 63;
  float dn = dinv[node];
  float a0 = dn*dn*xw[(size_t)node*DDv + 2*lane];
  float a1 = dn*dn*xw[(size_t)node*DDv + 2*lane+1];
  int e0 = min(max(off[node], 0), TOTE);
  int e1 = min(max(off[node+1], e0), TOTE);
  for(int e=e0; e<e1; e++){
    int s = min(max(esrc[e], 0), NNODE-1);
    float w = dinv[s]*dn;
    a0 = fmaf(w, xw[(size_t)s*DDv + 2*lane],   a0);
    a1 = fmaf(w, xw[(size_t)s*DDv + 2*lane+1], a1);
  }
  a0 += ldx(bias, 2*lane, f32); a1 += ldx(bias, 2*lane+1, f32);
  out[(size_t)node*DDv + 2*lane]   = fmaxf(a0, 0.f);
  out[(size_t)node*DDv + 2*lane+1] = fmaxf(a1, 0.f);
}

// ---- cross-attention per (b, head): fp32, per-thread online softmax ----
__global__ __launch_bounds__(256) void attn_k(const float* qg, const float* kg,
                                              const float* vg, float* og){
  __shared__ float Ks[512*16];
  __shared__ float Vs[512*16];
  int bh = blockIdx.x; int b = bh >> 3, hh = bh & 7;
  size_t base = (size_t)b*MMv*DDv + (size_t)hh*16;
  int t = threadIdx.x;
  for(int idx=t; idx<512*16; idx+=256){
    int kk = idx >> 4, i = idx & 15;
    Ks[idx] = kg[base + (size_t)kk*DDv + i];
    Vs[idx] = vg[base + (size_t)kk*DDv + i];
  }
  __syncthreads();
  for(int r=t; r<MMv; r+=256){
    float qr[16];
    #pragma unroll
    for(int i=0;i<16;i++) qr[i] = qg[base + (size_t)r*DDv + i];
    float m = -FLT_MAX, l = 0.f, acc[16] = {};
    for(int kk=0; kk<512; kk++){
      const float* kp = &Ks[kk*16];
      float s = 0.f;
      #pragma unroll
      for(int i=0;i<16;i++) s = fmaf(qr[i], kp[i], s);
      s *= 0.25f;
      float mn = fmaxf(m, s);
      float cold = __expf(m - mn);
      float p = __expf(s - mn);
      l = l*cold + p;
      const float* vp = &Vs[kk*16];
      #pragma unroll
      for(int i=0;i<16;i++) acc[i] = acc[i]*cold + p*vp[i];
      m = mn;
    }
    float inv = 1.0f/l;
    #pragma unroll
    for(int i=0;i<16;i++) og[base + (size_t)r*DDv + i] = acc[i]*inv;
  }
}

// ---- residual + LayerNorm: one thread per row, fp32 in/out; g/b dtype via DF ----
__global__ __launch_bounds__(256) void ln_k(const float* h, const float* delta,
                                            const void* g, int gdi, const void* bb, int bdi, int po,
                                            float* dst, const int* DF){
  int gf32 = DF[gdi], bf32 = DF[bdi];
  int row = blockIdx.x*256 + threadIdx.x;
  const float* hr = h + (size_t)row*DDv;
  const float* dr = delta + (size_t)row*DDv;
  float s = 0.f, ss = 0.f;
  for(int i=0;i<DDv;i++){
    float xv = hr[i] + dr[i];
    s += xv; ss = fmaf(xv, xv, ss);
  }
  float mu = s*(1.0f/DDv);
  float var = fmaxf(ss*(1.0f/DDv) - mu*mu, 0.f);
  float rs = 1.0f/sqrtf(var + 1e-5f);
  for(int i=0;i<DDv;i++){
    float xv = hr[i] + dr[i];
    dst[(size_t)row*DDv + i] = (xv - mu)*rs*ldx(g, po+i, gf32) + ldx(bb, po+i, bf32);
  }
}

// ---- enc -> fp32 h ----
__global__ __launch_bounds__(256) void cvt_k(const void* in, float* out, const int* DF){
  int f32 = DF[0];
  int tid = blockIdx.x*256 + threadIdx.x;
  out[tid] = ldx(in, tid, f32);
}

extern "C" void kernel_launch(void* const* d_in, const int* in_sizes, int n_in,
                              void* d_out, int out_size, void* d_ws, size_t ws_size,
                              hipStream_t stream) {
  if(n_in != 18){
    diag_fill_k<<<256, 256, 0, stream>>>((float*)d_out, out_size, 1000.0f);
    return;
  }
  const int expect[18] = {
    BB*MMv*DDv, BB*LLv*MMv, DDv*DDv, DDv, DDv*DDv, DDv,
    NLAY*DDv*DDv, NLAY*DDv*DDv, NLAY*DDv*DDv, NLAY*DDv*DDv,
    NLAY*DDv*DFFv, NLAY*DFFv, NLAY*DFFv*DDv, NLAY*DDv,
    NLAY*DDv, NLAY*DDv, NLAY*DDv, NLAY*DDv
  };
  for(int i=0;i<18;i++){
    if(in_sizes[i] != expect[i]){
      diag_fill_k<<<256, 256, 0, stream>>>((float*)d_out, out_size, 2000.0f + 10.0f*i);
      return;
    }
  }

  const void* enc  = d_in[0];
  const void* xe   = d_in[1];
  const void* c1W  = d_in[2];
  const void* c1b  = d_in[3];
  const void* c2W  = d_in[4];
  const void* c2b  = d_in[5];
  const void* Wq   = d_in[6];
  const void* Wk   = d_in[7];
  const void* Wv   = d_in[8];
  const void* Wo   = d_in[9];
  const void* W1   = d_in[10];
  const void* b1   = d_in[11];
  const void* W2   = d_in[12];
  const void* b2   = d_in[13];
  const void* ln1g = d_in[14];
  const void* ln1b = d_in[15];
  const void* ln2g = d_in[16];
  const void* ln2b = d_in[17];

  char* ws = (char*)d_ws;
  size_t o = 0;
  auto alloc = [&](size_t bytes){ size_t r = o; o = (o + bytes + 255) & ~(size_t)255; return r; };
  double* S64  = (double*)(ws + alloc((size_t)NNODE*8));
  double* R64  = (double*)(ws + alloc((size_t)NNODE*8));
  float* dinv  = (float*)(ws + alloc((size_t)NNODE*4));
  int*   cnt   = (int*)  (ws + alloc((size_t)NNODE*4));
  int*   cursor= (int*)  (ws + alloc((size_t)NNODE*4));
  int*   off   = (int*)  (ws + alloc((size_t)(NNODE+1)*4));
  int*   nbr   = (int*)  (ws + alloc((size_t)TOTE*4));
  int*   esrc  = (int*)  (ws + alloc((size_t)TOTE*4));
  int*   DF    = (int*)  (ws + alloc(256));
  const size_t ACTF = (size_t)NNODE*DDv*4;   // fp32 activation: 8.39 MB
  float* hF = (float*)(ws + alloc(ACTF));
  float* xg = (float*)(ws + alloc(ACTF));
  float* t0 = (float*)(ws + alloc(ACTF));
  float* t1 = (float*)(ws + alloc(ACTF));
  float* t2 = (float*)(ws + alloc(ACTF));    // t1+t2 contiguous -> ffn hidden fp32 [NNODE,DFF]
  float* t3 = (float*)(ws + alloc(ACTF));
  float* fb = t1;                             // 16.78 MB span; k/v dead when ffn runs
  // Xhi/Xlo (graph phase only) overlay hF..t1 — consumed by corrsel before cvt_k writes hF
  ushort_t* Xhi = (ushort_t*)hF;
  ushort_t* Xlo = Xhi + (size_t)BB*MMv*LLv;   // 16.78 MB each, spans 33.6 MB < 4*ACTF
  if(ws_size < o){
    diag_fill_k<<<256, 256, 0, stream>>>((float*)d_out, out_size, 3000.0f);
    return;
  }

  // ---- per-input dtype detection ----
  P18 pack;
  for(int i=0;i<18;i++){ pack.p[i] = (const ushort_t*)d_in[i]; pack.n[i] = in_sizes[i]; }
  ddet_k<<<18, 256, 0, stream>>>(pack, DF);

  // --- graph construction (split-bf16 MFMA corr + fp64 stats + selection) ---
  split_k<<<dim3(16,16,BB), dim3(32,8), 0, stream>>>(xe, Xhi, Xlo, DF);
  stats64_k<<<NNODE/256, 256, 0, stream>>>(xe, DF, S64, R64);
  corrsel_k<<<dim3(32, BB), 256, 0, stream>>>(Xhi, Xlo, S64, R64, nbr, DF);
  zero_k<<<NNODE/256, 256, 0, stream>>>(cnt);
  hist_k<<<TOTE/256, 256, 0, stream>>>(nbr, cnt);
  scan_k<<<1, 256, 0, stream>>>(cnt, off, cursor, dinv);
  fill_k<<<TOTE/256, 256, 0, stream>>>(nbr, cursor, esrc);

  // --- GCN (2 layers, fp32) ---
  cvt_k<<<NNODE*DDv/256, 256, 0, stream>>>(enc, hF, DF);
  gemm_k<<<dim3(2,256), dim3(16,16), 0, stream>>>(hF, c1W, 0, 2, nullptr, 0, 3, t0, DDv, DDv, 0, DF);
  agg_k<<<NNODE/4, 256, 0, stream>>>(t0, off, esrc, dinv, c1b, 3, t1, DF);
  gemm_k<<<dim3(2,256), dim3(16,16), 0, stream>>>(t1, c2W, 0, 4, nullptr, 0, 5, t0, DDv, DDv, 0, DF);
  agg_k<<<NNODE/4, 256, 0, stream>>>(t0, off, esrc, dinv, c2b, 5, xg, DF);

  // --- transformer (2 layers, fp32 end-to-end; query stream = hF, kv = xg) ---
  for(int l=0; l<NLAY; l++){
    gemm_k<<<dim3(2,256), dim3(16,16), 0, stream>>>(hF, Wq, (size_t)l*DDv*DDv, 6, nullptr, 0, 6, t0, DDv, DDv, 0, DF);
    gemm_k<<<dim3(2,256), dim3(16,16), 0, stream>>>(xg, Wk, (size_t)l*DDv*DDv, 7, nullptr, 0, 7, t1, DDv, DDv, 0, DF);
    gemm_k<<<dim3(2,256), dim3(16,16), 0, stream>>>(xg, Wv, (size_t)l*DDv*DDv, 8, nullptr, 0, 8, t2, DDv, DDv, 0, DF);
    attn_k<<<BB*HHv, 256, 0, stream>>>(t0, t1, t2, t3);
    gemm_k<<<dim3(2,256), dim3(16,16), 0, stream>>>(t3, Wo, (size_t)l*DDv*DDv, 9, nullptr, 0, 9, t0, DDv, DDv, 0, DF);
    ln_k<<<NNODE/256, 256, 0, stream>>>(hF, t0, ln1g, 14, ln1b, 15, l*DDv, hF, DF);
    gemm_k<<<dim3(4,256), dim3(16,16), 0, stream>>>(hF, W1, (size_t)l*DDv*DFFv, 10, b1, l*DFFv, 11, fb, DDv, DFFv, 1, DF);
    gemm_k<<<dim3(2,256), dim3(16,16), 0, stream>>>(fb, W2, (size_t)l*DFFv*DDv, 12, b2, l*DDv, 13, t0, DFFv, DDv, 0, DF);
    float* dst = (l == NLAY-1) ? (float*)d_out : hF;
    ln_k<<<NNODE/256, 256, 0, stream>>>(hF, t0, ln2g, 16, ln2b, 17, l*DDv, dst, DF);
  }
}